// Round 3
// baseline (1229.542 us; speedup 1.0000x reference)
//
#include <hip/hip_runtime.h>

#define N_EDGE 262144
#define N_TRI  1048576
#define DIM    128
#define NRBF   6
#define ADIM   49
#define NBIL   8
#define TE     64
#define NTHR   512
#define LDA_F  132   // f32 row stride (528 B) — keeps rows 16B-aligned, spreads banks

typedef __attribute__((ext_vector_type(8))) short bf16x8;
typedef __attribute__((ext_vector_type(4))) float f32x4;

__device__ __forceinline__ float silu_f(float x) { return x / (1.f + __expf(-x)); }
__device__ __forceinline__ unsigned short f2bf(float f) {
    unsigned int u = __float_as_uint(f);
    return (unsigned short)((u + 0x7FFFu + ((u >> 16) & 1u)) >> 16);
}
__device__ __forceinline__ unsigned int pk2(float x, float y) {
    unsigned int r;
    asm("v_cvt_pk_bf16_f32 %0, %1, %2" : "=v"(r) : "v"(x), "v"(y));
    return r;
}
__device__ __forceinline__ bf16x8 pack8(const float* p) {
    float4 a = *(const float4*)p;
    float4 b = *(const float4*)(p + 4);
    union { bf16x8 v; unsigned int w[4]; } u;
    u.w[0] = pk2(a.x, a.y); u.w[1] = pk2(a.z, a.w);
    u.w[2] = pk2(b.x, b.y); u.w[3] = pk2(b.z, b.w);
    return u.v;
}

// ---------------------------------------------------------------------------
// prep: 9 DxD weights -> bf16 transposed [n][k]; final_w -> bf16 direct cast
// slots: 0=nbr_m_w 1=m_ji_w 2=post_w 3..8=res_w(6) then fwb [128][1024]
// ---------------------------------------------------------------------------
__global__ __launch_bounds__(256) void prep_w_k(
    const float* __restrict__ nbr, const float* __restrict__ mji,
    const float* __restrict__ post, const float* __restrict__ res,
    const float* __restrict__ fw, unsigned short* __restrict__ wt)
{
    int idx = blockIdx.x * 256 + threadIdx.x;          // 278528 total
    if (idx < 9 * 16384) {
        int m = idx >> 14, rr = idx & 16383;
        int n = rr >> 7, k = rr & 127;
        const float* src = (m == 0) ? nbr : (m == 1) ? mji : (m == 2) ? post
                          : (res + (size_t)(m - 3) * 16384);
        wt[idx] = f2bf(src[k * DIM + n]);
    } else {
        wt[idx] = f2bf(fw[idx - 9 * 16384]);           // [i][j*128+l] == [n][k]
    }
}

// ---------------------------------------------------------------------------
// triplet stage: t_a = a_sbf @ a_sbf_w; atomic segment-sum into ta copy
// (blockIdx & (nc-1)) -> XCD-local copy, kills cross-XCD line ping-pong
// ---------------------------------------------------------------------------
__global__ __launch_bounds__(256) void triplet_ta_k(
    const float* __restrict__ a_sbf, const float* __restrict__ a_sbf_w,
    const int* __restrict__ kj_idx, float* __restrict__ ta_sum, int nc)
{
    __shared__ __align__(16) float sA[256 * ADIM];
    __shared__ float sWa[ADIM * NBIL];
    const int tid = threadIdx.x;
    const size_t w0 = (size_t)blockIdx.x * 256;

    {
        const float4* src = (const float4*)(a_sbf + w0 * ADIM);
        float4* dst = (float4*)sA;
        const int n4 = (256 * ADIM) / 4;
        for (int i = tid; i < n4; i += 256) dst[i] = src[i];
    }
    for (int i = tid; i < ADIM * NBIL; i += 256) sWa[i] = a_sbf_w[i];
    __syncthreads();

    float ta[NBIL];
    #pragma unroll
    for (int j = 0; j < NBIL; ++j) ta[j] = 0.0f;
    const float* row = sA + tid * ADIM;
    #pragma unroll
    for (int k = 0; k < ADIM; ++k) {
        float v = row[k];
        #pragma unroll
        for (int j = 0; j < NBIL; ++j) ta[j] = fmaf(v, sWa[k * NBIL + j], ta[j]);
    }
    const int e = kj_idx[w0 + tid];
    float* dst = ta_sum + (size_t)(blockIdx.x & (nc - 1)) * (N_EDGE * NBIL)
               + (size_t)e * NBIL;
    #pragma unroll
    for (int j = 0; j < NBIL; ++j) atomicAdd(dst + j, ta[j]);
}

// ---------------------------------------------------------------------------
// fused edge kernel: 8 waves (2M x 4N), TE=64. f32 LDS round-trips, bf16
// A-pack via v_cvt_pk_bf16_f32, static B-fragment prefetch one stage ahead.
// ---------------------------------------------------------------------------
__global__ __launch_bounds__(NTHR, 4) void edge_main_k(
    const float* __restrict__ m_ji, const float* __restrict__ e_rbf,
    const float* __restrict__ ta_sum, int nc, const unsigned short* __restrict__ wt,
    const float* __restrict__ nbr_m_b, const float* __restrict__ e_rbf_w,
    const float* __restrict__ m_ji_b, const float* __restrict__ post_b,
    const float* __restrict__ res_b, float* __restrict__ out)
{
    __shared__ __align__(16) float sX[TE * LDA_F];   // activations (f32)
    __shared__ __align__(16) float sT[TE * LDA_F];   // transf (f32)
    __shared__ float sTA[TE * NBIL];
    __shared__ float sE[TE * NRBF];
    __shared__ float sEw[NRBF * DIM];
    __shared__ float sBias[9 * DIM];

    const int tid  = threadIdx.x;
    const int lane = tid & 63;
    const int ml   = lane & 15;
    const int g    = lane >> 4;
    const int wid  = tid >> 6;
    const int mb   = (wid >> 2) * 32;
    const int n0   = (wid & 3) * 32;
    const size_t e0 = (size_t)blockIdx.x * TE;

    // ---- prologue staging
    #pragma unroll
    for (int i = 0; i < 4; ++i) {
        int c = tid + i * NTHR;                       // 2048 float4 chunks
        int row = c >> 5, cc = c & 31;
        *(float4*)(sX + row * LDA_F + cc * 4) =
            *(const float4*)(m_ji + (e0 + row) * DIM + cc * 4);
    }
    {
        float s = 0.f;
        for (int c = 0; c < nc; ++c)
            s += ta_sum[(size_t)c * (N_EDGE * NBIL) + e0 * NBIL + tid];
        sTA[tid] = s;                                 // TE*8 == 512
    }
    if (tid < TE * NRBF) sE[tid] = e_rbf[e0 * NRBF + tid];
    for (int i = tid; i < NRBF * DIM; i += NTHR) sEw[i] = e_rbf_w[i];
    for (int i = tid; i < 9 * DIM; i += NTHR) {
        int seg = i >> 7, off = i & 127;
        const float* p = (seg == 0) ? nbr_m_b : (seg == 1) ? m_ji_b
                       : (seg == 2) ? post_b : (res_b + (seg - 3) * DIM);
        sBias[i] = p[off];
    }
    __syncthreads();

    bf16x8 A[2][4], Bf[2][4];
    f32x4 acc[2][2], xr[2][2];

    auto load_a = [&]() {
        #pragma unroll
        for (int mt = 0; mt < 2; ++mt) {
            const float* rb = sX + (mb + mt * 16 + ml) * LDA_F + g * 8;
            #pragma unroll
            for (int ks = 0; ks < 4; ++ks) A[mt][ks] = pack8(rb + ks * 32);
        }
    };
    auto prefB = [&](const unsigned short* wtm, int ldk, int kbase) {
        #pragma unroll
        for (int nt = 0; nt < 2; ++nt) {
            const unsigned short* wb =
                wtm + (size_t)(n0 + nt * 16 + ml) * ldk + kbase + g * 8;
            #pragma unroll
            for (int ks = 0; ks < 4; ++ks)
                Bf[nt][ks] = *(const bf16x8*)(wb + ks * 32);
        }
    };
    auto mfma_run = [&]() {
        #pragma unroll
        for (int nt = 0; nt < 2; ++nt)
        #pragma unroll
        for (int ks = 0; ks < 4; ++ks) {
            acc[0][nt] = __builtin_amdgcn_mfma_f32_16x16x32_bf16(A[0][ks], Bf[nt][ks], acc[0][nt], 0, 0, 0);
            acc[1][nt] = __builtin_amdgcn_mfma_f32_16x16x32_bf16(A[1][ks], Bf[nt][ks], acc[1][nt], 0, 0, 0);
        }
    };
    auto init_bias = [&](int slot) {
        #pragma unroll
        for (int nt = 0; nt < 2; ++nt) {
            float bv = sBias[slot * DIM + n0 + nt * 16 + ml];
            #pragma unroll
            for (int r = 0; r < 4; ++r) { acc[0][nt][r] = bv; acc[1][nt][r] = bv; }
        }
    };
    auto store_arr = [&](f32x4 (&v)[2][2]) {          // -> sX, guarded
        __syncthreads();
        #pragma unroll
        for (int mt = 0; mt < 2; ++mt)
        #pragma unroll
        for (int r = 0; r < 4; ++r) {
            int row = mb + mt * 16 + g * 4 + r;
            #pragma unroll
            for (int nt = 0; nt < 2; ++nt)
                sX[row * LDA_F + n0 + nt * 16 + ml] = v[mt][nt][r];
        }
        __syncthreads();
    };

    // ---- transf = silu(m_ji @ m_ji_w + b) -> sT
    prefB(wt + 1 * 16384, DIM, 0);
    load_a();                                         // A = bf16(m_ji)
    init_bias(1);
    mfma_run();
    prefB(wt + 0 * 16384, DIM, 0);                    // nbr weights next
    #pragma unroll
    for (int mt = 0; mt < 2; ++mt)
    #pragma unroll
    for (int r = 0; r < 4; ++r) {
        int row = mb + mt * 16 + g * 4 + r;
        #pragma unroll
        for (int nt = 0; nt < 2; ++nt)
            sT[row * LDA_F + n0 + nt * 16 + ml] = silu_f(acc[mt][nt][r]);
    }

    // ---- me = silu(m_ji @ nbr_m_w + b) * (e_rbf @ e_rbf_w)   (A unchanged)
    init_bias(0);
    mfma_run();
    const unsigned short* fwb = wt + 9 * 16384;
    prefB(fwb, NBIL * DIM, 0);                        // bilinear j=0
    {
        float ewc[2][NRBF];
        #pragma unroll
        for (int nt = 0; nt < 2; ++nt)
        #pragma unroll
        for (int q = 0; q < NRBF; ++q) ewc[nt][q] = sEw[q * DIM + n0 + nt * 16 + ml];
        #pragma unroll
        for (int mt = 0; mt < 2; ++mt)
        #pragma unroll
        for (int r = 0; r < 4; ++r) {
            int row = mb + mt * 16 + g * 4 + r;
            float er[NRBF];
            #pragma unroll
            for (int q = 0; q < NRBF; ++q) er[q] = sE[row * NRBF + q];
            #pragma unroll
            for (int nt = 0; nt < 2; ++nt) {
                float te = 0.f;
                #pragma unroll
                for (int q = 0; q < NRBF; ++q) te = fmaf(er[q], ewc[nt][q], te);
                acc[mt][nt][r] = silu_f(acc[mt][nt][r]) * te;
            }
        }
    }
    store_arr(acc);                                   // sX = me
    load_a();                                         // A = bf16(me)

    // ---- bilinear: xr = transf + sum_j ta_j * (me @ fw_j^T)
    #pragma unroll
    for (int mt = 0; mt < 2; ++mt)
    #pragma unroll
    for (int r = 0; r < 4; ++r) {
        int row = mb + mt * 16 + g * 4 + r;
        #pragma unroll
        for (int nt = 0; nt < 2; ++nt)
            xr[mt][nt][r] = sT[row * LDA_F + n0 + nt * 16 + ml];
    }
    for (int j = 0; j < NBIL; ++j) {
        #pragma unroll
        for (int mt = 0; mt < 2; ++mt)
        #pragma unroll
        for (int nt = 0; nt < 2; ++nt)
        #pragma unroll
        for (int r = 0; r < 4; ++r) acc[mt][nt][r] = 0.f;
        mfma_run();
        if (j < NBIL - 1) prefB(fwb, NBIL * DIM, (j + 1) * DIM);
        else              prefB(wt + 3 * 16384, DIM, 0);
        #pragma unroll
        for (int mt = 0; mt < 2; ++mt) {
            float tv[4];
            #pragma unroll
            for (int r = 0; r < 4; ++r)
                tv[r] = sTA[(mb + mt * 16 + g * 4 + r) * NBIL + j];
            #pragma unroll
            for (int nt = 0; nt < 2; ++nt)
            #pragma unroll
            for (int r = 0; r < 4; ++r)
                xr[mt][nt][r] = fmaf(tv[r], acc[mt][nt][r], xr[mt][nt][r]);
        }
    }
    store_arr(xr);                                    // sX = x

    // ---- res0
    load_a(); init_bias(3); mfma_run(); prefB(wt + 4 * 16384, DIM, 0);
    #pragma unroll
    for (int mt = 0; mt < 2; ++mt)
    #pragma unroll
    for (int nt = 0; nt < 2; ++nt)
    #pragma unroll
    for (int r = 0; r < 4; ++r) acc[mt][nt][r] = silu_f(acc[mt][nt][r]);
    store_arr(acc);
    load_a(); init_bias(4); mfma_run(); prefB(wt + 2 * 16384, DIM, 0);
    #pragma unroll
    for (int mt = 0; mt < 2; ++mt)
    #pragma unroll
    for (int nt = 0; nt < 2; ++nt)
    #pragma unroll
    for (int r = 0; r < 4; ++r) xr[mt][nt][r] += silu_f(acc[mt][nt][r]);
    store_arr(xr);

    // ---- post: x = silu(x @ post_w + b) + transf
    load_a(); init_bias(2); mfma_run(); prefB(wt + 5 * 16384, DIM, 0);
    #pragma unroll
    for (int mt = 0; mt < 2; ++mt)
    #pragma unroll
    for (int r = 0; r < 4; ++r) {
        int row = mb + mt * 16 + g * 4 + r;
        #pragma unroll
        for (int nt = 0; nt < 2; ++nt)
            xr[mt][nt][r] = silu_f(acc[mt][nt][r]) + sT[row * LDA_F + n0 + nt * 16 + ml];
    }
    store_arr(xr);

    // ---- res1
    load_a(); init_bias(5); mfma_run(); prefB(wt + 6 * 16384, DIM, 0);
    #pragma unroll
    for (int mt = 0; mt < 2; ++mt)
    #pragma unroll
    for (int nt = 0; nt < 2; ++nt)
    #pragma unroll
    for (int r = 0; r < 4; ++r) acc[mt][nt][r] = silu_f(acc[mt][nt][r]);
    store_arr(acc);
    load_a(); init_bias(6); mfma_run(); prefB(wt + 7 * 16384, DIM, 0);
    #pragma unroll
    for (int mt = 0; mt < 2; ++mt)
    #pragma unroll
    for (int nt = 0; nt < 2; ++nt)
    #pragma unroll
    for (int r = 0; r < 4; ++r) xr[mt][nt][r] += silu_f(acc[mt][nt][r]);
    store_arr(xr);

    // ---- res2, second half fused with global store
    load_a(); init_bias(7); mfma_run(); prefB(wt + 8 * 16384, DIM, 0);
    #pragma unroll
    for (int mt = 0; mt < 2; ++mt)
    #pragma unroll
    for (int nt = 0; nt < 2; ++nt)
    #pragma unroll
    for (int r = 0; r < 4; ++r) acc[mt][nt][r] = silu_f(acc[mt][nt][r]);
    store_arr(acc);
    load_a(); init_bias(8); mfma_run();
    #pragma unroll
    for (int mt = 0; mt < 2; ++mt)
    #pragma unroll
    for (int r = 0; r < 4; ++r) {
        int row = mb + mt * 16 + g * 4 + r;
        #pragma unroll
        for (int nt = 0; nt < 2; ++nt)
            out[(e0 + row) * DIM + n0 + nt * 16 + ml] =
                silu_f(acc[mt][nt][r]) + xr[mt][nt][r];
    }
}

// ---------------------------------------------------------------------------
extern "C" void kernel_launch(void* const* d_in, const int* in_sizes, int n_in,
                              void* d_out, int out_size, void* d_ws, size_t ws_size,
                              hipStream_t stream)
{
    (void)in_sizes; (void)n_in; (void)out_size;
    const float* m_ji    = (const float*)d_in[0];
    const float* e_rbf   = (const float*)d_in[1];
    const float* a_sbf   = (const float*)d_in[2];
    const int*   kj_idx  = (const int*)d_in[5];
    const float* nbr_m_w = (const float*)d_in[6];
    const float* nbr_m_b = (const float*)d_in[7];
    const float* e_rbf_w = (const float*)d_in[8];
    const float* a_sbf_w = (const float*)d_in[9];
    const float* final_w = (const float*)d_in[10];
    const float* m_ji_w  = (const float*)d_in[11];
    const float* m_ji_b  = (const float*)d_in[12];
    const float* post_w  = (const float*)d_in[13];
    const float* post_b  = (const float*)d_in[14];
    const float* res_w   = (const float*)d_in[15];
    const float* res_b   = (const float*)d_in[16];
    float* out = (float*)d_out;

    const size_t taB = (size_t)N_EDGE * NBIL * sizeof(float);
    const size_t wtB = (size_t)278528 * sizeof(unsigned short);
    const int nc = (ws_size >= 8 * taB + wtB) ? 8 : 1;   // XCD-local copies

    float* ta = (float*)d_ws;
    unsigned short* wt = (unsigned short*)((char*)d_ws + (size_t)nc * taB);

    hipMemsetAsync(ta, 0, (size_t)nc * taB, stream);
    prep_w_k<<<1088, 256, 0, stream>>>(nbr_m_w, m_ji_w, post_w, res_w, final_w, wt);
    triplet_ta_k<<<N_TRI / 256, 256, 0, stream>>>(a_sbf, a_sbf_w, kj_idx, ta, nc);
    edge_main_k<<<N_EDGE / TE, NTHR, 0, stream>>>(m_ji, e_rbf, ta, nc, wt,
        nbr_m_b, e_rbf_w, m_ji_b, post_b, res_b, out);
}

// Round 4
// 793.250 us; speedup vs baseline: 1.5500x; 1.5500x over previous
//
#include <hip/hip_runtime.h>

#define N_EDGE 262144
#define N_TRI  1048576
#define DIM    128
#define NRBF   6
#define ADIM   49
#define NBIL   8
#define TE     64
#define NTHR   256
#define LDA    136   // bf16 row stride (272 B)
#define LDT    136
#define LDTA   9

typedef __attribute__((ext_vector_type(8))) short bf16x8;
typedef __attribute__((ext_vector_type(4))) float f32x4;

__device__ __forceinline__ float silu_f(float x) { return x / (1.f + __expf(-x)); }
__device__ __forceinline__ unsigned short f2bf(float f) {
    unsigned int u = __float_as_uint(f);
    return (unsigned short)((u + 0x7FFFu + ((u >> 16) & 1u)) >> 16);
}
__device__ __forceinline__ unsigned int pk2(float x, float y) {
    unsigned int r;
    asm("v_cvt_pk_bf16_f32 %0, %1, %2" : "=v"(r) : "v"(x), "v"(y));
    return r;
}
__device__ __forceinline__ bf16x8 pack8(const float* p) {
    float4 a = *(const float4*)p;
    float4 b = *(const float4*)(p + 4);
    union { bf16x8 v; unsigned int w[4]; } u;
    u.w[0] = pk2(a.x, a.y); u.w[1] = pk2(a.z, a.w);
    u.w[2] = pk2(b.x, b.y); u.w[3] = pk2(b.z, b.w);
    return u.v;
}
__device__ __forceinline__ float bf2f(unsigned short u) {
    return __uint_as_float(((unsigned int)u) << 16);
}

// ---------------------------------------------------------------------------
// prep: 9 DxD weights -> bf16 transposed [n][k]; final_w -> bf16 direct cast
// slots: 0=nbr_m_w 1=m_ji_w 2=post_w 3..8=res_w(6) then fwb [128][1024]
// ---------------------------------------------------------------------------
__global__ __launch_bounds__(256) void prep_w_k(
    const float* __restrict__ nbr, const float* __restrict__ mji,
    const float* __restrict__ post, const float* __restrict__ res,
    const float* __restrict__ fw, unsigned short* __restrict__ wt)
{
    int idx = blockIdx.x * 256 + threadIdx.x;          // 278528 total
    if (idx < 9 * 16384) {
        int m = idx >> 14, rr = idx & 16383;
        int n = rr >> 7, k = rr & 127;
        const float* src = (m == 0) ? nbr : (m == 1) ? mji : (m == 2) ? post
                          : (res + (size_t)(m - 3) * 16384);
        wt[idx] = f2bf(src[k * DIM + n]);
    } else {
        wt[idx] = f2bf(fw[idx - 9 * 16384]);           // [i][j*128+l] == [n][k]
    }
}

// ---------------------------------------------------------------------------
// triplet stage: hardware f32 atomics (fire-and-forget), no CAS loop
// ---------------------------------------------------------------------------
__global__ __launch_bounds__(256) void triplet_ta_k(
    const float* __restrict__ a_sbf, const float* __restrict__ a_sbf_w,
    const int* __restrict__ kj_idx, float* __restrict__ ta_sum)
{
    __shared__ __align__(16) float sA[256 * ADIM];
    __shared__ float sWa[ADIM * NBIL];
    const int tid = threadIdx.x;
    const size_t w0 = (size_t)blockIdx.x * 256;

    {
        const float4* src = (const float4*)(a_sbf + w0 * ADIM);
        float4* dst = (float4*)sA;
        const int n4 = (256 * ADIM) / 4;
        for (int i = tid; i < n4; i += 256) dst[i] = src[i];
    }
    for (int i = tid; i < ADIM * NBIL; i += 256) sWa[i] = a_sbf_w[i];
    __syncthreads();

    float ta[NBIL];
    #pragma unroll
    for (int j = 0; j < NBIL; ++j) ta[j] = 0.0f;
    const float* row = sA + tid * ADIM;
    #pragma unroll
    for (int k = 0; k < ADIM; ++k) {
        float v = row[k];
        #pragma unroll
        for (int j = 0; j < NBIL; ++j) ta[j] = fmaf(v, sWa[k * NBIL + j], ta[j]);
    }
    const int e = kj_idx[w0 + tid];
    float* dst = ta_sum + (size_t)e * NBIL;
    #pragma unroll
    for (int j = 0; j < NBIL; ++j) unsafeAtomicAdd(dst + j, ta[j]);
}

// ---------------------------------------------------------------------------
// fused edge kernel: TE=64, 4 waves; wave w owns rows 0..63 x cols [w*32,+32).
// bf16 LDS activations, split-K A loads, B prefetched one stage ahead.
// ---------------------------------------------------------------------------
__global__ __launch_bounds__(NTHR) void edge_main_k(
    const float* __restrict__ m_ji, const float* __restrict__ e_rbf,
    const float* __restrict__ ta_sum, const unsigned short* __restrict__ wt,
    const float* __restrict__ nbr_m_b, const float* __restrict__ e_rbf_w,
    const float* __restrict__ m_ji_b, const float* __restrict__ post_b,
    const float* __restrict__ res_b, float* __restrict__ out)
{
    __shared__ __align__(16) unsigned short sXb[TE * LDA];   // activations bf16
    __shared__ __align__(16) unsigned short sTb[TE * LDT];   // transf bf16
    __shared__ float sTA[TE * LDTA];
    __shared__ float sE[TE * NRBF];
    __shared__ float sEw[NRBF * DIM];
    __shared__ float sBias[9 * DIM];

    const int tid  = threadIdx.x;
    const int lane = tid & 63;
    const int ml   = lane & 15;
    const int g    = lane >> 4;
    const int n0   = (tid >> 6) * 32;
    const size_t e0 = (size_t)blockIdx.x * TE;

    bf16x8 A[4][2], Bf[2][4];
    f32x4 acc[4][2], xr[4][2];

    auto prefB = [&](const unsigned short* wtm, int ldk, int kbase) {
        #pragma unroll
        for (int nt = 0; nt < 2; ++nt) {
            const unsigned short* wb =
                wtm + (size_t)(n0 + nt * 16 + ml) * ldk + kbase + g * 8;
            #pragma unroll
            for (int ks = 0; ks < 4; ++ks)
                Bf[nt][ks] = *(const bf16x8*)(wb + ks * 32);
        }
    };

    // ---- prologue: issue first B prefetch immediately, then stage LDS
    prefB(wt + 1 * 16384, DIM, 0);                     // m_ji_w for stage 1

    #pragma unroll
    for (int i = 0; i < 4; ++i) {
        int c = tid + i * NTHR;                        // 1024 bf16x8 chunks
        int row = c >> 4, cc = c & 15;
        const float* src = m_ji + (e0 + row) * DIM + cc * 8;
        *(bf16x8*)(sXb + row * LDA + cc * 8) = pack8(src);
    }
    #pragma unroll
    for (int i = 0; i < 2; ++i) {
        int idx = tid + i * NTHR;                      // 512 ta values
        int e = idx >> 3, jj = idx & 7;
        sTA[e * LDTA + jj] = ta_sum[(e0 + e) * NBIL + jj];
    }
    if (tid < 128) {
        int e = tid >> 1, h = tid & 1;                 // 64 edges x 6 rbf
        if (h == 0) { sE[e*NRBF+0]=e_rbf[(e0+e)*NRBF+0]; sE[e*NRBF+1]=e_rbf[(e0+e)*NRBF+1]; sE[e*NRBF+2]=e_rbf[(e0+e)*NRBF+2]; }
        else        { sE[e*NRBF+3]=e_rbf[(e0+e)*NRBF+3]; sE[e*NRBF+4]=e_rbf[(e0+e)*NRBF+4]; sE[e*NRBF+5]=e_rbf[(e0+e)*NRBF+5]; }
    }
    for (int i = tid; i < NRBF * DIM; i += NTHR) sEw[i] = e_rbf_w[i];
    for (int i = tid; i < 9 * DIM; i += NTHR) {
        int seg = i >> 7, off = i & 127;
        const float* p = (seg == 0) ? nbr_m_b : (seg == 1) ? m_ji_b
                       : (seg == 2) ? post_b : (res_b + (seg - 3) * DIM);
        sBias[i] = p[off];
    }
    __syncthreads();

    auto loadA = [&](int h) {
        #pragma unroll
        for (int mt = 0; mt < 4; ++mt) {
            const unsigned short* rb = sXb + (mt * 16 + ml) * LDA + h * 64 + g * 8;
            A[mt][0] = *(const bf16x8*)(rb);
            A[mt][1] = *(const bf16x8*)(rb + 32);
        }
    };
    auto mfmaH = [&](int h) {
        #pragma unroll
        for (int nt = 0; nt < 2; ++nt)
        #pragma unroll
        for (int kk = 0; kk < 2; ++kk) {
            #pragma unroll
            for (int mt = 0; mt < 4; ++mt)
                acc[mt][nt] = __builtin_amdgcn_mfma_f32_16x16x32_bf16(
                    A[mt][kk], Bf[nt][h * 2 + kk], acc[mt][nt], 0, 0, 0);
        }
    };
    auto gemm_full = [&]() { loadA(0); mfmaH(0); loadA(1); mfmaH(1); };
    auto init_bias = [&](int slot) {
        #pragma unroll
        for (int nt = 0; nt < 2; ++nt) {
            float bv = sBias[slot * DIM + n0 + nt * 16 + ml];
            #pragma unroll
            for (int mt = 0; mt < 4; ++mt)
            #pragma unroll
            for (int r = 0; r < 4; ++r) acc[mt][nt][r] = bv;
        }
    };
    auto store_sX = [&](f32x4 (&v)[4][2]) {            // bf16 -> sXb, guarded
        __syncthreads();
        #pragma unroll
        for (int mt = 0; mt < 4; ++mt)
        #pragma unroll
        for (int r = 0; r < 4; ++r) {
            int base = (mt * 16 + g * 4 + r) * LDA + n0 + ml;
            sXb[base]      = (unsigned short)pk2(v[mt][0][r], v[mt][0][r]);
            sXb[base + 16] = (unsigned short)pk2(v[mt][1][r], v[mt][1][r]);
        }
        __syncthreads();
    };

    // ---- stage 1: transf = silu(m_ji @ m_ji_w + b) -> sTb
    init_bias(1);
    gemm_full();
    prefB(wt + 0 * 16384, DIM, 0);                     // nbr_m_w next
    #pragma unroll
    for (int mt = 0; mt < 4; ++mt)
    #pragma unroll
    for (int r = 0; r < 4; ++r) {
        int base = (mt * 16 + g * 4 + r) * LDT + n0 + ml;
        float t0 = silu_f(acc[mt][0][r]), t1 = silu_f(acc[mt][1][r]);
        sTb[base]      = (unsigned short)pk2(t0, t0);
        sTb[base + 16] = (unsigned short)pk2(t1, t1);
    }

    // ---- stage 2: me = silu(m_ji @ nbr_m_w + b) * (e_rbf @ e_rbf_w)
    init_bias(0);
    gemm_full();
    const unsigned short* fwb = wt + 9 * 16384;
    prefB(fwb, NBIL * DIM, 0);                         // bilinear j=0
    {
        float ewc[2][NRBF];
        #pragma unroll
        for (int nt = 0; nt < 2; ++nt)
        #pragma unroll
        for (int q = 0; q < NRBF; ++q) ewc[nt][q] = sEw[q * DIM + n0 + nt * 16 + ml];
        #pragma unroll
        for (int mt = 0; mt < 4; ++mt)
        #pragma unroll
        for (int r = 0; r < 4; ++r) {
            int row = mt * 16 + g * 4 + r;
            float er[NRBF];
            #pragma unroll
            for (int q = 0; q < NRBF; ++q) er[q] = sE[row * NRBF + q];
            #pragma unroll
            for (int nt = 0; nt < 2; ++nt) {
                float te = 0.f;
                #pragma unroll
                for (int q = 0; q < NRBF; ++q) te = fmaf(er[q], ewc[nt][q], te);
                acc[mt][nt][r] = silu_f(acc[mt][nt][r]) * te;
            }
        }
    }
    store_sX(acc);                                     // sXb = me

    // ---- bilinear: xr = transf + sum_j ta_j * (me @ fw_j^T)
    #pragma unroll
    for (int mt = 0; mt < 4; ++mt)
    #pragma unroll
    for (int r = 0; r < 4; ++r) {
        int base = (mt * 16 + g * 4 + r) * LDT + n0 + ml;
        xr[mt][0][r] = bf2f(sTb[base]);
        xr[mt][1][r] = bf2f(sTb[base + 16]);
    }
    for (int j = 0; j < NBIL; ++j) {
        #pragma unroll
        for (int mt = 0; mt < 4; ++mt)
        #pragma unroll
        for (int nt = 0; nt < 2; ++nt)
        #pragma unroll
        for (int r = 0; r < 4; ++r) acc[mt][nt][r] = 0.f;
        gemm_full();
        if (j < NBIL - 1) prefB(fwb, NBIL * DIM, (j + 1) * DIM);
        else              prefB(wt + 3 * 16384, DIM, 0);
        #pragma unroll
        for (int mt = 0; mt < 4; ++mt) {
            float tv[4];
            #pragma unroll
            for (int r = 0; r < 4; ++r)
                tv[r] = sTA[(mt * 16 + g * 4 + r) * LDTA + j];
            #pragma unroll
            for (int nt = 0; nt < 2; ++nt)
            #pragma unroll
            for (int r = 0; r < 4; ++r)
                xr[mt][nt][r] = fmaf(tv[r], acc[mt][nt][r], xr[mt][nt][r]);
        }
    }
    store_sX(xr);                                      // sXb = x

    // ---- res0
    init_bias(3); gemm_full(); prefB(wt + 4 * 16384, DIM, 0);
    #pragma unroll
    for (int mt = 0; mt < 4; ++mt)
    #pragma unroll
    for (int nt = 0; nt < 2; ++nt)
    #pragma unroll
    for (int r = 0; r < 4; ++r) acc[mt][nt][r] = silu_f(acc[mt][nt][r]);
    store_sX(acc);
    init_bias(4); gemm_full(); prefB(wt + 2 * 16384, DIM, 0);
    #pragma unroll
    for (int mt = 0; mt < 4; ++mt)
    #pragma unroll
    for (int nt = 0; nt < 2; ++nt)
    #pragma unroll
    for (int r = 0; r < 4; ++r) xr[mt][nt][r] += silu_f(acc[mt][nt][r]);
    store_sX(xr);

    // ---- post: x = silu(x @ post_w + b) + transf
    init_bias(2); gemm_full(); prefB(wt + 5 * 16384, DIM, 0);
    #pragma unroll
    for (int mt = 0; mt < 4; ++mt)
    #pragma unroll
    for (int r = 0; r < 4; ++r) {
        int base = (mt * 16 + g * 4 + r) * LDT + n0 + ml;
        xr[mt][0][r] = silu_f(acc[mt][0][r]) + bf2f(sTb[base]);
        xr[mt][1][r] = silu_f(acc[mt][1][r]) + bf2f(sTb[base + 16]);
    }
    store_sX(xr);

    // ---- res1
    init_bias(5); gemm_full(); prefB(wt + 6 * 16384, DIM, 0);
    #pragma unroll
    for (int mt = 0; mt < 4; ++mt)
    #pragma unroll
    for (int nt = 0; nt < 2; ++nt)
    #pragma unroll
    for (int r = 0; r < 4; ++r) acc[mt][nt][r] = silu_f(acc[mt][nt][r]);
    store_sX(acc);
    init_bias(6); gemm_full(); prefB(wt + 7 * 16384, DIM, 0);
    #pragma unroll
    for (int mt = 0; mt < 4; ++mt)
    #pragma unroll
    for (int nt = 0; nt < 2; ++nt)
    #pragma unroll
    for (int r = 0; r < 4; ++r) xr[mt][nt][r] += silu_f(acc[mt][nt][r]);
    store_sX(xr);

    // ---- res2, second half fused with global store
    init_bias(7); gemm_full(); prefB(wt + 8 * 16384, DIM, 0);
    #pragma unroll
    for (int mt = 0; mt < 4; ++mt)
    #pragma unroll
    for (int nt = 0; nt < 2; ++nt)
    #pragma unroll
    for (int r = 0; r < 4; ++r) acc[mt][nt][r] = silu_f(acc[mt][nt][r]);
    store_sX(acc);
    init_bias(8); gemm_full();
    #pragma unroll
    for (int mt = 0; mt < 4; ++mt)
    #pragma unroll
    for (int r = 0; r < 4; ++r) {
        int row = mt * 16 + g * 4 + r;
        out[(e0 + row) * DIM + n0 + ml]      = silu_f(acc[mt][0][r]) + xr[mt][0][r];
        out[(e0 + row) * DIM + n0 + 16 + ml] = silu_f(acc[mt][1][r]) + xr[mt][1][r];
    }
}

// ---------------------------------------------------------------------------
extern "C" void kernel_launch(void* const* d_in, const int* in_sizes, int n_in,
                              void* d_out, int out_size, void* d_ws, size_t ws_size,
                              hipStream_t stream)
{
    (void)in_sizes; (void)n_in; (void)out_size; (void)ws_size;
    const float* m_ji    = (const float*)d_in[0];
    const float* e_rbf   = (const float*)d_in[1];
    const float* a_sbf   = (const float*)d_in[2];
    const int*   kj_idx  = (const int*)d_in[5];
    const float* nbr_m_w = (const float*)d_in[6];
    const float* nbr_m_b = (const float*)d_in[7];
    const float* e_rbf_w = (const float*)d_in[8];
    const float* a_sbf_w = (const float*)d_in[9];
    const float* final_w = (const float*)d_in[10];
    const float* m_ji_w  = (const float*)d_in[11];
    const float* m_ji_b  = (const float*)d_in[12];
    const float* post_w  = (const float*)d_in[13];
    const float* post_b  = (const float*)d_in[14];
    const float* res_w   = (const float*)d_in[15];
    const float* res_b   = (const float*)d_in[16];
    float* out = (float*)d_out;

    const size_t taB = (size_t)N_EDGE * NBIL * sizeof(float);
    float* ta = (float*)d_ws;
    unsigned short* wt = (unsigned short*)((char*)d_ws + taB);

    hipMemsetAsync(ta, 0, taB, stream);
    prep_w_k<<<1088, 256, 0, stream>>>(nbr_m_w, m_ji_w, post_w, res_w, final_w, wt);
    triplet_ta_k<<<N_TRI / 256, 256, 0, stream>>>(a_sbf, a_sbf_w, kj_idx, ta);
    edge_main_k<<<N_EDGE / TE, NTHR, 0, stream>>>(m_ji, e_rbf, ta, wt,
        nbr_m_b, e_rbf_w, m_ji_b, post_b, res_b, out);
}

// Round 5
// 580.787 us; speedup vs baseline: 2.1170x; 1.3658x over previous
//
#include <hip/hip_runtime.h>

#define N_EDGE 262144
#define N_TRI  1048576
#define DIM    128
#define NRBF   6
#define ADIM   49
#define NBIL   8
#define TE     64
#define NTHR   256
#define LDA    136   // bf16 row stride (272 B)
#define LDT    136
#define LDTA   9
#define EB     1024  // edges per seg_reduce block

typedef __attribute__((ext_vector_type(8))) short bf16x8;
typedef __attribute__((ext_vector_type(4))) float f32x4;

__device__ __forceinline__ float silu_f(float x) { return x / (1.f + __expf(-x)); }
__device__ __forceinline__ unsigned short f2bf(float f) {
    unsigned int u = __float_as_uint(f);
    return (unsigned short)((u + 0x7FFFu + ((u >> 16) & 1u)) >> 16);
}
__device__ __forceinline__ unsigned int pk2(float x, float y) {
    unsigned int r;
    asm("v_cvt_pk_bf16_f32 %0, %1, %2" : "=v"(r) : "v"(x), "v"(y));
    return r;
}
__device__ __forceinline__ bf16x8 pack8(const float* p) {
    float4 a = *(const float4*)p;
    float4 b = *(const float4*)(p + 4);
    union { bf16x8 v; unsigned int w[4]; } u;
    u.w[0] = pk2(a.x, a.y); u.w[1] = pk2(a.z, a.w);
    u.w[2] = pk2(b.x, b.y); u.w[3] = pk2(b.z, b.w);
    return u.v;
}
__device__ __forceinline__ float bf2f(unsigned short u) {
    return __uint_as_float(((unsigned int)u) << 16);
}

// ---------------------------------------------------------------------------
// prep: 9 DxD weights -> bf16 transposed [n][k]; final_w -> bf16 direct cast
// ---------------------------------------------------------------------------
__global__ __launch_bounds__(256) void prep_w_k(
    const float* __restrict__ nbr, const float* __restrict__ mji,
    const float* __restrict__ post, const float* __restrict__ res,
    const float* __restrict__ fw, unsigned short* __restrict__ wt)
{
    int idx = blockIdx.x * 256 + threadIdx.x;          // 278528 total
    if (idx < 9 * 16384) {
        int m = idx >> 14, rr = idx & 16383;
        int n = rr >> 7, k = rr & 127;
        const float* src = (m == 0) ? nbr : (m == 1) ? mji : (m == 2) ? post
                          : (res + (size_t)(m - 3) * 16384);
        wt[idx] = f2bf(src[k * DIM + n]);
    } else {
        wt[idx] = f2bf(fw[idx - 9 * 16384]);           // [i][j*128+l] == [n][k]
    }
}

// ---------------------------------------------------------------------------
// triplet stage A: ta[w][8] = a_sbf[w] @ a_sbf_w  (coalesced write, no atomics)
// ---------------------------------------------------------------------------
__global__ __launch_bounds__(256) void ta_all_k(
    const float* __restrict__ a_sbf, const float* __restrict__ a_sbf_w,
    float* __restrict__ taw)
{
    __shared__ __align__(16) float sA[256 * ADIM];
    __shared__ float sWa[ADIM * NBIL];
    const int tid = threadIdx.x;
    const size_t w0 = (size_t)blockIdx.x * 256;

    {
        const float4* src = (const float4*)(a_sbf + w0 * ADIM);
        float4* dst = (float4*)sA;
        const int n4 = (256 * ADIM) / 4;
        for (int i = tid; i < n4; i += 256) dst[i] = src[i];
    }
    for (int i = tid; i < ADIM * NBIL; i += 256) sWa[i] = a_sbf_w[i];
    __syncthreads();

    float ta[NBIL];
    #pragma unroll
    for (int j = 0; j < NBIL; ++j) ta[j] = 0.0f;
    const float* row = sA + tid * ADIM;
    #pragma unroll
    for (int k = 0; k < ADIM; ++k) {
        float v = row[k];
        #pragma unroll
        for (int j = 0; j < NBIL; ++j) ta[j] = fmaf(v, sWa[k * NBIL + j], ta[j]);
    }
    float4* dst = (float4*)(taw + (w0 + tid) * NBIL);
    dst[0] = make_float4(ta[0], ta[1], ta[2], ta[3]);
    dst[1] = make_float4(ta[4], ta[5], ta[6], ta[7]);
}

// ---------------------------------------------------------------------------
// triplet stage B: per-block LDS bin over 1024 edges; stream kj_idx, gather
// matching ta rows, LDS-atomic accumulate, coalesced writeback. No global
// atomics anywhere.
// ---------------------------------------------------------------------------
__global__ __launch_bounds__(1024) void seg_reduce_k(
    const float* __restrict__ taw, const int* __restrict__ kj_idx,
    float* __restrict__ ta_sum)
{
    __shared__ float acc[EB * NBIL];                   // 32 KB
    const int tid = threadIdx.x;
    const int lo = blockIdx.x * EB;

    #pragma unroll
    for (int i = tid; i < EB * NBIL; i += 1024) acc[i] = 0.f;
    __syncthreads();

    const int4* kj4 = (const int4*)kj_idx;
    #pragma unroll 4
    for (int i = tid; i < N_TRI / 4; i += 1024) {
        int4 v = kj4[i];
        int w0 = i * 4;
        #pragma unroll
        for (int k = 0; k < 4; ++k) {
            int e = (k == 0) ? v.x : (k == 1) ? v.y : (k == 2) ? v.z : v.w;
            unsigned d = (unsigned)(e - lo);
            if (d < (unsigned)EB) {
                const float4* p = (const float4*)(taw + (size_t)(w0 + k) * NBIL);
                float4 a = p[0], b = p[1];
                float* q = acc + d * NBIL;
                atomicAdd(q + 0, a.x); atomicAdd(q + 1, a.y);
                atomicAdd(q + 2, a.z); atomicAdd(q + 3, a.w);
                atomicAdd(q + 4, b.x); atomicAdd(q + 5, b.y);
                atomicAdd(q + 6, b.z); atomicAdd(q + 7, b.w);
            }
        }
    }
    __syncthreads();
    float4* dst = (float4*)(ta_sum + (size_t)lo * NBIL);
    const float4* s4 = (const float4*)acc;
    #pragma unroll
    for (int i = tid; i < EB * NBIL / 4; i += 1024) dst[i] = s4[i];
}

// ---------------------------------------------------------------------------
// fallback triplet (scattered hw atomics) when ws too small for taw
// ---------------------------------------------------------------------------
__global__ __launch_bounds__(256) void triplet_atomic_k(
    const float* __restrict__ a_sbf, const float* __restrict__ a_sbf_w,
    const int* __restrict__ kj_idx, float* __restrict__ ta_sum)
{
    __shared__ __align__(16) float sA[256 * ADIM];
    __shared__ float sWa[ADIM * NBIL];
    const int tid = threadIdx.x;
    const size_t w0 = (size_t)blockIdx.x * 256;
    {
        const float4* src = (const float4*)(a_sbf + w0 * ADIM);
        float4* dst = (float4*)sA;
        for (int i = tid; i < (256 * ADIM) / 4; i += 256) dst[i] = src[i];
    }
    for (int i = tid; i < ADIM * NBIL; i += 256) sWa[i] = a_sbf_w[i];
    __syncthreads();
    float ta[NBIL];
    #pragma unroll
    for (int j = 0; j < NBIL; ++j) ta[j] = 0.0f;
    const float* row = sA + tid * ADIM;
    #pragma unroll
    for (int k = 0; k < ADIM; ++k) {
        float v = row[k];
        #pragma unroll
        for (int j = 0; j < NBIL; ++j) ta[j] = fmaf(v, sWa[k * NBIL + j], ta[j]);
    }
    const int e = kj_idx[w0 + tid];
    float* dst = ta_sum + (size_t)e * NBIL;
    #pragma unroll
    for (int j = 0; j < NBIL; ++j) unsafeAtomicAdd(dst + j, ta[j]);
}

// ---------------------------------------------------------------------------
// fused edge kernel (unchanged from round 4)
// ---------------------------------------------------------------------------
__global__ __launch_bounds__(NTHR) void edge_main_k(
    const float* __restrict__ m_ji, const float* __restrict__ e_rbf,
    const float* __restrict__ ta_sum, const unsigned short* __restrict__ wt,
    const float* __restrict__ nbr_m_b, const float* __restrict__ e_rbf_w,
    const float* __restrict__ m_ji_b, const float* __restrict__ post_b,
    const float* __restrict__ res_b, float* __restrict__ out)
{
    __shared__ __align__(16) unsigned short sXb[TE * LDA];
    __shared__ __align__(16) unsigned short sTb[TE * LDT];
    __shared__ float sTA[TE * LDTA];
    __shared__ float sE[TE * NRBF];
    __shared__ float sEw[NRBF * DIM];
    __shared__ float sBias[9 * DIM];

    const int tid  = threadIdx.x;
    const int lane = tid & 63;
    const int ml   = lane & 15;
    const int g    = lane >> 4;
    const int n0   = (tid >> 6) * 32;
    const size_t e0 = (size_t)blockIdx.x * TE;

    bf16x8 A[4][2], Bf[2][4];
    f32x4 acc[4][2], xr[4][2];

    auto prefB = [&](const unsigned short* wtm, int ldk, int kbase) {
        #pragma unroll
        for (int nt = 0; nt < 2; ++nt) {
            const unsigned short* wb =
                wtm + (size_t)(n0 + nt * 16 + ml) * ldk + kbase + g * 8;
            #pragma unroll
            for (int ks = 0; ks < 4; ++ks)
                Bf[nt][ks] = *(const bf16x8*)(wb + ks * 32);
        }
    };

    prefB(wt + 1 * 16384, DIM, 0);                     // m_ji_w for stage 1

    #pragma unroll
    for (int i = 0; i < 4; ++i) {
        int c = tid + i * NTHR;
        int row = c >> 4, cc = c & 15;
        const float* src = m_ji + (e0 + row) * DIM + cc * 8;
        *(bf16x8*)(sXb + row * LDA + cc * 8) = pack8(src);
    }
    #pragma unroll
    for (int i = 0; i < 2; ++i) {
        int idx = tid + i * NTHR;
        int e = idx >> 3, jj = idx & 7;
        sTA[e * LDTA + jj] = ta_sum[(e0 + e) * NBIL + jj];
    }
    if (tid < 128) {
        int e = tid >> 1, h = tid & 1;
        if (h == 0) { sE[e*NRBF+0]=e_rbf[(e0+e)*NRBF+0]; sE[e*NRBF+1]=e_rbf[(e0+e)*NRBF+1]; sE[e*NRBF+2]=e_rbf[(e0+e)*NRBF+2]; }
        else        { sE[e*NRBF+3]=e_rbf[(e0+e)*NRBF+3]; sE[e*NRBF+4]=e_rbf[(e0+e)*NRBF+4]; sE[e*NRBF+5]=e_rbf[(e0+e)*NRBF+5]; }
    }
    for (int i = tid; i < NRBF * DIM; i += NTHR) sEw[i] = e_rbf_w[i];
    for (int i = tid; i < 9 * DIM; i += NTHR) {
        int seg = i >> 7, off = i & 127;
        const float* p = (seg == 0) ? nbr_m_b : (seg == 1) ? m_ji_b
                       : (seg == 2) ? post_b : (res_b + (seg - 3) * DIM);
        sBias[i] = p[off];
    }
    __syncthreads();

    auto loadA = [&](int h) {
        #pragma unroll
        for (int mt = 0; mt < 4; ++mt) {
            const unsigned short* rb = sXb + (mt * 16 + ml) * LDA + h * 64 + g * 8;
            A[mt][0] = *(const bf16x8*)(rb);
            A[mt][1] = *(const bf16x8*)(rb + 32);
        }
    };
    auto mfmaH = [&](int h) {
        #pragma unroll
        for (int nt = 0; nt < 2; ++nt)
        #pragma unroll
        for (int kk = 0; kk < 2; ++kk) {
            #pragma unroll
            for (int mt = 0; mt < 4; ++mt)
                acc[mt][nt] = __builtin_amdgcn_mfma_f32_16x16x32_bf16(
                    A[mt][kk], Bf[nt][h * 2 + kk], acc[mt][nt], 0, 0, 0);
        }
    };
    auto gemm_full = [&]() { loadA(0); mfmaH(0); loadA(1); mfmaH(1); };
    auto init_bias = [&](int slot) {
        #pragma unroll
        for (int nt = 0; nt < 2; ++nt) {
            float bv = sBias[slot * DIM + n0 + nt * 16 + ml];
            #pragma unroll
            for (int mt = 0; mt < 4; ++mt)
            #pragma unroll
            for (int r = 0; r < 4; ++r) acc[mt][nt][r] = bv;
        }
    };
    auto store_sX = [&](f32x4 (&v)[4][2]) {
        __syncthreads();
        #pragma unroll
        for (int mt = 0; mt < 4; ++mt)
        #pragma unroll
        for (int r = 0; r < 4; ++r) {
            int base = (mt * 16 + g * 4 + r) * LDA + n0 + ml;
            sXb[base]      = (unsigned short)pk2(v[mt][0][r], v[mt][0][r]);
            sXb[base + 16] = (unsigned short)pk2(v[mt][1][r], v[mt][1][r]);
        }
        __syncthreads();
    };

    // ---- stage 1: transf = silu(m_ji @ m_ji_w + b) -> sTb
    init_bias(1);
    gemm_full();
    prefB(wt + 0 * 16384, DIM, 0);
    #pragma unroll
    for (int mt = 0; mt < 4; ++mt)
    #pragma unroll
    for (int r = 0; r < 4; ++r) {
        int base = (mt * 16 + g * 4 + r) * LDT + n0 + ml;
        float t0 = silu_f(acc[mt][0][r]), t1 = silu_f(acc[mt][1][r]);
        sTb[base]      = (unsigned short)pk2(t0, t0);
        sTb[base + 16] = (unsigned short)pk2(t1, t1);
    }

    // ---- stage 2: me = silu(m_ji @ nbr_m_w + b) * (e_rbf @ e_rbf_w)
    init_bias(0);
    gemm_full();
    const unsigned short* fwb = wt + 9 * 16384;
    prefB(fwb, NBIL * DIM, 0);
    {
        float ewc[2][NRBF];
        #pragma unroll
        for (int nt = 0; nt < 2; ++nt)
        #pragma unroll
        for (int q = 0; q < NRBF; ++q) ewc[nt][q] = sEw[q * DIM + n0 + nt * 16 + ml];
        #pragma unroll
        for (int mt = 0; mt < 4; ++mt)
        #pragma unroll
        for (int r = 0; r < 4; ++r) {
            int row = mt * 16 + g * 4 + r;
            float er[NRBF];
            #pragma unroll
            for (int q = 0; q < NRBF; ++q) er[q] = sE[row * NRBF + q];
            #pragma unroll
            for (int nt = 0; nt < 2; ++nt) {
                float te = 0.f;
                #pragma unroll
                for (int q = 0; q < NRBF; ++q) te = fmaf(er[q], ewc[nt][q], te);
                acc[mt][nt][r] = silu_f(acc[mt][nt][r]) * te;
            }
        }
    }
    store_sX(acc);

    // ---- bilinear
    #pragma unroll
    for (int mt = 0; mt < 4; ++mt)
    #pragma unroll
    for (int r = 0; r < 4; ++r) {
        int base = (mt * 16 + g * 4 + r) * LDT + n0 + ml;
        xr[mt][0][r] = bf2f(sTb[base]);
        xr[mt][1][r] = bf2f(sTb[base + 16]);
    }
    for (int j = 0; j < NBIL; ++j) {
        #pragma unroll
        for (int mt = 0; mt < 4; ++mt)
        #pragma unroll
        for (int nt = 0; nt < 2; ++nt)
        #pragma unroll
        for (int r = 0; r < 4; ++r) acc[mt][nt][r] = 0.f;
        gemm_full();
        if (j < NBIL - 1) prefB(fwb, NBIL * DIM, (j + 1) * DIM);
        else              prefB(wt + 3 * 16384, DIM, 0);
        #pragma unroll
        for (int mt = 0; mt < 4; ++mt) {
            float tv[4];
            #pragma unroll
            for (int r = 0; r < 4; ++r)
                tv[r] = sTA[(mt * 16 + g * 4 + r) * LDTA + j];
            #pragma unroll
            for (int nt = 0; nt < 2; ++nt)
            #pragma unroll
            for (int r = 0; r < 4; ++r)
                xr[mt][nt][r] = fmaf(tv[r], acc[mt][nt][r], xr[mt][nt][r]);
        }
    }
    store_sX(xr);

    // ---- res0
    init_bias(3); gemm_full(); prefB(wt + 4 * 16384, DIM, 0);
    #pragma unroll
    for (int mt = 0; mt < 4; ++mt)
    #pragma unroll
    for (int nt = 0; nt < 2; ++nt)
    #pragma unroll
    for (int r = 0; r < 4; ++r) acc[mt][nt][r] = silu_f(acc[mt][nt][r]);
    store_sX(acc);
    init_bias(4); gemm_full(); prefB(wt + 2 * 16384, DIM, 0);
    #pragma unroll
    for (int mt = 0; mt < 4; ++mt)
    #pragma unroll
    for (int nt = 0; nt < 2; ++nt)
    #pragma unroll
    for (int r = 0; r < 4; ++r) xr[mt][nt][r] += silu_f(acc[mt][nt][r]);
    store_sX(xr);

    // ---- post
    init_bias(2); gemm_full(); prefB(wt + 5 * 16384, DIM, 0);
    #pragma unroll
    for (int mt = 0; mt < 4; ++mt)
    #pragma unroll
    for (int r = 0; r < 4; ++r) {
        int base = (mt * 16 + g * 4 + r) * LDT + n0 + ml;
        xr[mt][0][r] = silu_f(acc[mt][0][r]) + bf2f(sTb[base]);
        xr[mt][1][r] = silu_f(acc[mt][1][r]) + bf2f(sTb[base + 16]);
    }
    store_sX(xr);

    // ---- res1
    init_bias(5); gemm_full(); prefB(wt + 6 * 16384, DIM, 0);
    #pragma unroll
    for (int mt = 0; mt < 4; ++mt)
    #pragma unroll
    for (int nt = 0; nt < 2; ++nt)
    #pragma unroll
    for (int r = 0; r < 4; ++r) acc[mt][nt][r] = silu_f(acc[mt][nt][r]);
    store_sX(acc);
    init_bias(6); gemm_full(); prefB(wt + 7 * 16384, DIM, 0);
    #pragma unroll
    for (int mt = 0; mt < 4; ++mt)
    #pragma unroll
    for (int nt = 0; nt < 2; ++nt)
    #pragma unroll
    for (int r = 0; r < 4; ++r) xr[mt][nt][r] += silu_f(acc[mt][nt][r]);
    store_sX(xr);

    // ---- res2 + store
    init_bias(7); gemm_full(); prefB(wt + 8 * 16384, DIM, 0);
    #pragma unroll
    for (int mt = 0; mt < 4; ++mt)
    #pragma unroll
    for (int nt = 0; nt < 2; ++nt)
    #pragma unroll
    for (int r = 0; r < 4; ++r) acc[mt][nt][r] = silu_f(acc[mt][nt][r]);
    store_sX(acc);
    init_bias(8); gemm_full();
    #pragma unroll
    for (int mt = 0; mt < 4; ++mt)
    #pragma unroll
    for (int r = 0; r < 4; ++r) {
        int row = mt * 16 + g * 4 + r;
        out[(e0 + row) * DIM + n0 + ml]      = silu_f(acc[mt][0][r]) + xr[mt][0][r];
        out[(e0 + row) * DIM + n0 + 16 + ml] = silu_f(acc[mt][1][r]) + xr[mt][1][r];
    }
}

// ---------------------------------------------------------------------------
extern "C" void kernel_launch(void* const* d_in, const int* in_sizes, int n_in,
                              void* d_out, int out_size, void* d_ws, size_t ws_size,
                              hipStream_t stream)
{
    (void)in_sizes; (void)n_in; (void)out_size;
    const float* m_ji    = (const float*)d_in[0];
    const float* e_rbf   = (const float*)d_in[1];
    const float* a_sbf   = (const float*)d_in[2];
    const int*   kj_idx  = (const int*)d_in[5];
    const float* nbr_m_w = (const float*)d_in[6];
    const float* nbr_m_b = (const float*)d_in[7];
    const float* e_rbf_w = (const float*)d_in[8];
    const float* a_sbf_w = (const float*)d_in[9];
    const float* final_w = (const float*)d_in[10];
    const float* m_ji_w  = (const float*)d_in[11];
    const float* m_ji_b  = (const float*)d_in[12];
    const float* post_w  = (const float*)d_in[13];
    const float* post_b  = (const float*)d_in[14];
    const float* res_w   = (const float*)d_in[15];
    const float* res_b   = (const float*)d_in[16];
    float* out = (float*)d_out;

    const size_t taB  = (size_t)N_EDGE * NBIL * sizeof(float);      // 8.4 MB
    const size_t wtB  = (size_t)278528 * sizeof(unsigned short);    // 0.56 MB
    const size_t tawB = (size_t)N_TRI * NBIL * sizeof(float);       // 33.6 MB

    float* ta_sum = (float*)d_ws;
    unsigned short* wt = (unsigned short*)((char*)d_ws + taB);
    float* taw = (float*)((char*)d_ws + taB + wtB);

    prep_w_k<<<1088, 256, 0, stream>>>(nbr_m_w, m_ji_w, post_w, res_w, final_w, wt);

    if (ws_size >= taB + wtB + tawB) {
        ta_all_k<<<N_TRI / 256, 256, 0, stream>>>(a_sbf, a_sbf_w, taw);
        seg_reduce_k<<<N_EDGE / EB, 1024, 0, stream>>>(taw, kj_idx, ta_sum);
    } else {
        hipMemsetAsync(ta_sum, 0, taB, stream);
        triplet_atomic_k<<<N_TRI / 256, 256, 0, stream>>>(a_sbf, a_sbf_w, kj_idx, ta_sum);
    }
    edge_main_k<<<N_EDGE / TE, NTHR, 0, stream>>>(m_ji, e_rbf, ta_sum, wt,
        nbr_m_b, e_rbf_w, m_ji_b, post_b, res_b, out);
}